// Round 5
// baseline (447.017 us; speedup 1.0000x reference)
//
#include <hip/hip_runtime.h>
#include <math.h>

// Router: x (4,8192,1024) f32, W (64,1024) f32
// out = [ top_idx (32768,2) as float | top_gates (32768,2) | loss (1) ]
// ws  = 64 floats of per-expert prob sums (atomic accumulated)
//
// R5 = R4 + hand software-pipelined W loads.
// R4 post-mortem: ~3100 cy/kg-step vs 128 cy FMA; compiler kept only one
// kg's W float4s in flight (VGPR=100/256 used) -> exposed VMEM latency every
// kg. Fix: explicit ping-pong register banks wv0/wv1, kg loop manually 2x
// unrolled, prefetch kg+1 (8x W global_load_dwordx4 + 2x x ds_read_b128)
// issued before the 64-FMA block on the current bank.

constexpr int DMODEL = 1024;
constexpr int NEXP   = 64;
constexpr int BM     = 128;   // tokens per block
constexpr int BK     = 64;    // K per tile
constexpr int NWAVE  = 8;
constexpr int NTOK   = 32768;
constexpr int NTILE  = DMODEL / BK;  // 16

__device__ __forceinline__ void gload16(const float* g, float* l) {
    __builtin_amdgcn_global_load_lds(
        (const __attribute__((address_space(1))) unsigned int*)g,
        (__attribute__((address_space(3))) unsigned int*)l,
        16, 0, 0);
}

__global__ __launch_bounds__(512, 2) void router_kernel(
    const float* __restrict__ x, const float* __restrict__ W,
    float* __restrict__ out, float* __restrict__ expert_sums)
{
    // xs[buf][row][64 floats]; row r stores logical 16B-chunk c at phys chunk c ^ (r&15)
    __shared__ __align__(16) float xs[2][BM][BK];
    __shared__ float lmax[NWAVE][BM];
    __shared__ float lsum[NWAVE][BM];
    __shared__ float ltv[NWAVE][BM][2];
    __shared__ int   lti[NWAVE][BM][2];

    const int tid  = threadIdx.x;
    const int lane = tid & 63;
    const int w    = tid >> 6;           // wave id 0..7
    const int tok0 = blockIdx.x * BM;

    // divergent-typed W base (vector loads, vmcnt pipe); wave-uniform value
    const float* Wb = W + (size_t)(tid >> 6) * (8 * DMODEL);

    float4 acc0[8], acc1[8];
#pragma unroll
    for (int e = 0; e < 8; ++e) {
        acc0[e] = make_float4(0.f, 0.f, 0.f, 0.f);
        acc1[e] = make_float4(0.f, 0.f, 0.f, 0.f);
    }

    // ---- staging: wave w stages rows [w*16, w*16+16) via 4 instrs x 4 rows ----
    auto stage = [&](int buf, int tile) {
#pragma unroll
        for (int i = 0; i < 4; ++i) {
            const int r0 = w * 16 + i * 4;
            const int r  = r0 + (lane >> 4);
            const int c  = lane & 15;
            const float* src = x + (size_t)(tok0 + r) * DMODEL + tile * BK
                                 + ((c ^ (r & 15)) << 2);
            float* dst = &xs[buf][r0][0] + (lane << 2);
            gload16(src, dst);
        }
    };

    stage(0, 0);
    __syncthreads();

    const int swb = lane & 15;
    int cur = 0;
    for (int tile = 0; tile < NTILE; ++tile) {
        if (tile + 1 < NTILE) stage(cur ^ 1, tile + 1);
        const float* WbT = Wb + tile * BK;

        float4 wv0[8], wv1[8];
        float4 xa0, xa1, xb0, xb1;

        // prologue: kg=0 into bank0
#pragma unroll
        for (int e = 0; e < 8; ++e)
            wv0[e] = *reinterpret_cast<const float4*>(WbT + e * DMODEL);
        {
            const int sw = (0 ^ swb) << 2;
            xa0 = *reinterpret_cast<const float4*>(&xs[cur][lane][sw]);
            xa1 = *reinterpret_cast<const float4*>(&xs[cur][lane + 64][sw]);
        }

#pragma unroll
        for (int kg2 = 0; kg2 < 8; ++kg2) {
            const int kgB = 2 * kg2 + 1;
            // prefetch kgB into bank1 (issued before FMA on bank0)
#pragma unroll
            for (int e = 0; e < 8; ++e)
                wv1[e] = *reinterpret_cast<const float4*>(
                    WbT + e * DMODEL + (kgB << 2));
            {
                const int sw = (kgB ^ swb) << 2;
                xb0 = *reinterpret_cast<const float4*>(&xs[cur][lane][sw]);
                xb1 = *reinterpret_cast<const float4*>(&xs[cur][lane + 64][sw]);
            }
            // FMA on bank0 (kg = 2*kg2)
#pragma unroll
            for (int e = 0; e < 8; ++e) {
                acc0[e].x = fmaf(xa0.x, wv0[e].x, acc0[e].x);
                acc0[e].y = fmaf(xa0.y, wv0[e].y, acc0[e].y);
                acc0[e].z = fmaf(xa0.z, wv0[e].z, acc0[e].z);
                acc0[e].w = fmaf(xa0.w, wv0[e].w, acc0[e].w);
                acc1[e].x = fmaf(xa1.x, wv0[e].x, acc1[e].x);
                acc1[e].y = fmaf(xa1.y, wv0[e].y, acc1[e].y);
                acc1[e].z = fmaf(xa1.z, wv0[e].z, acc1[e].z);
                acc1[e].w = fmaf(xa1.w, wv0[e].w, acc1[e].w);
            }
            // prefetch kg=2*kg2+2 into bank0
            if (kg2 < 7) {
                const int kgN = 2 * kg2 + 2;
#pragma unroll
                for (int e = 0; e < 8; ++e)
                    wv0[e] = *reinterpret_cast<const float4*>(
                        WbT + e * DMODEL + (kgN << 2));
                const int sw = (kgN ^ swb) << 2;
                xa0 = *reinterpret_cast<const float4*>(&xs[cur][lane][sw]);
                xa1 = *reinterpret_cast<const float4*>(&xs[cur][lane + 64][sw]);
            }
            // FMA on bank1 (kg = 2*kg2+1)
#pragma unroll
            for (int e = 0; e < 8; ++e) {
                acc0[e].x = fmaf(xb0.x, wv1[e].x, acc0[e].x);
                acc0[e].y = fmaf(xb0.y, wv1[e].y, acc0[e].y);
                acc0[e].z = fmaf(xb0.z, wv1[e].z, acc0[e].z);
                acc0[e].w = fmaf(xb0.w, wv1[e].w, acc0[e].w);
                acc1[e].x = fmaf(xb1.x, wv1[e].x, acc1[e].x);
                acc1[e].y = fmaf(xb1.y, wv1[e].y, acc1[e].y);
                acc1[e].z = fmaf(xb1.z, wv1[e].z, acc1[e].z);
                acc1[e].w = fmaf(xb1.w, wv1[e].w, acc1[e].w);
            }
        }
        __syncthreads();   // stage(t+1) drained + buf reuse guard
        cur ^= 1;
    }

    // ---- epilogue: tokens t0 = tok0+lane, t1 = tok0+lane+64 ----
    float l0[8], l1[8];
    float m0 = -INFINITY, m1 = -INFINITY;
#pragma unroll
    for (int e = 0; e < 8; ++e) {
        l0[e] = (acc0[e].x + acc0[e].y) + (acc0[e].z + acc0[e].w);
        l1[e] = (acc1[e].x + acc1[e].y) + (acc1[e].z + acc1[e].w);
        m0 = fmaxf(m0, l0[e]);
        m1 = fmaxf(m1, l1[e]);
    }
    lmax[w][lane] = m0;
    lmax[w][lane + 64] = m1;
    __syncthreads();

    float g0 = -INFINITY, g1 = -INFINITY;
#pragma unroll
    for (int ww = 0; ww < NWAVE; ++ww) {
        g0 = fmaxf(g0, lmax[ww][lane]);
        g1 = fmaxf(g1, lmax[ww][lane + 64]);
    }

    float p0[8], p1[8];
    float s0 = 0.f, s1 = 0.f;
#pragma unroll
    for (int e = 0; e < 8; ++e) {
        p0[e] = __expf(l0[e] - g0); s0 += p0[e];
        p1[e] = __expf(l1[e] - g1); s1 += p1[e];
    }
    lsum[w][lane] = s0;
    lsum[w][lane + 64] = s1;

    // local top-2 per token over this wave's 8 experts (value desc, index asc)
    {
        float v0 = -INFINITY, v1 = -INFINITY; int i0 = NEXP, i1 = NEXP;
        float u0 = -INFINITY, u1 = -INFINITY; int j0 = NEXP, j1 = NEXP;
#pragma unroll
        for (int e = 0; e < 8; ++e) {
            const int gi = w * 8 + e;
            float v = l0[e];
            if (v > v0) { v1 = v0; i1 = i0; v0 = v; i0 = gi; }
            else if (v > v1) { v1 = v; i1 = gi; }
            float u = l1[e];
            if (u > u0) { u1 = u0; j1 = j0; u0 = u; j0 = gi; }
            else if (u > u1) { u1 = u; j1 = gi; }
        }
        ltv[w][lane][0] = v0; ltv[w][lane][1] = v1;
        lti[w][lane][0] = i0; lti[w][lane][1] = i1;
        ltv[w][lane + 64][0] = u0; ltv[w][lane + 64][1] = u1;
        lti[w][lane + 64][0] = j0; lti[w][lane + 64][1] = j1;
    }
    __syncthreads();

    float gs0 = 0.f, gs1 = 0.f;
#pragma unroll
    for (int ww = 0; ww < NWAVE; ++ww) {
        gs0 += lsum[ww][lane];
        gs1 += lsum[ww][lane + 64];
    }
    const float inv0 = 1.0f / gs0;
    const float inv1 = 1.0f / gs1;

    // per-expert prob sums over this block's 128 tokens -> 1 atomic per (wave, e)
#pragma unroll
    for (int e = 0; e < 8; ++e) {
        float v = p0[e] * inv0 + p1[e] * inv1;
#pragma unroll
        for (int off = 32; off; off >>= 1) v += __shfl_xor(v, off, 64);
        if (lane == 0) atomicAdd(&expert_sums[w * 8 + e], v);
    }

    // waves 0-1 merge the 8 waves' candidates and write idx + gates
    if (tid < BM) {
        const int t = tid;
        float bv0 = -INFINITY, bv1 = -INFINITY;
        int   bi0 = NEXP, bi1 = NEXP;
#pragma unroll
        for (int ww = 0; ww < NWAVE; ++ww) {
#pragma unroll
            for (int j = 0; j < 2; ++j) {
                float v  = ltv[ww][t][j];
                int   gi = lti[ww][t][j];
                bool b0 = (v > bv0) || (v == bv0 && gi < bi0);
                if (b0) { bv1 = bv0; bi1 = bi0; bv0 = v; bi0 = gi; }
                else {
                    bool b1 = (v > bv1) || (v == bv1 && gi < bi1);
                    if (b1) { bv1 = v; bi1 = gi; }
                }
            }
        }
        float g     = __expf(bv1 - bv0);
        float denom = 1.0f + g;
        float ga = 1.0f / denom;
        float gb = g / denom;

        size_t tok = (size_t)tok0 + t;
        reinterpret_cast<float2*>(out)[tok]            = make_float2((float)bi0, (float)bi1);
        reinterpret_cast<float2*>(out + 2 * NTOK)[tok] = make_float2(ga, gb);
    }
}

__global__ void loss_kernel(const float* __restrict__ sums, float* __restrict__ out)
{
    const int lane = threadIdx.x;  // 64 threads
    float pv = sums[lane] * (1.0f / (float)NTOK);  // avg_probs[lane]
    float m = pv;
#pragma unroll
    for (int off = 32; off; off >>= 1) m += __shfl_xor(m, off, 64);
    m *= (1.0f / (float)NEXP);
    float d = pv - m;
    float v = d * d;
#pragma unroll
    for (int off = 32; off; off >>= 1) v += __shfl_xor(v, off, 64);
    v *= (1.0f / (float)(NEXP - 1));  // ddof=1
    if (lane == 0) {
        float stdv = sqrtf(v);
        float r = stdv / (m + 1e-6f);
        out[4 * NTOK] = r * r;
    }
}

extern "C" void kernel_launch(void* const* d_in, const int* in_sizes, int n_in,
                              void* d_out, int out_size, void* d_ws, size_t ws_size,
                              hipStream_t stream)
{
    const float* x = (const float*)d_in[0];
    const float* W = (const float*)d_in[1];
    float* out  = (float*)d_out;
    float* sums = (float*)d_ws;

    hipMemsetAsync(d_ws, 0, NEXP * sizeof(float), stream);

    hipLaunchKernelGGL(router_kernel, dim3(NTOK / BM), dim3(512), 0, stream,
                       x, W, out, sums);
    hipLaunchKernelGGL(loss_kernel, dim3(1), dim3(64), 0, stream, sums, out);
}

// Round 6
// 446.748 us; speedup vs baseline: 1.0006x; 1.0006x over previous
//
#include <hip/hip_runtime.h>
#include <math.h>

// Router: x (4,8192,1024) f32, W (64,1024) f32
// out = [ top_idx (32768,2) as float | top_gates (32768,2) | loss (1) ]
// ws  = 64 floats of per-expert prob sums (atomic accumulated)
//
// R6 = R5 ping-pong pipeline + __launch_bounds__(512,1).
// Measured across R3/R4/R5: launch_bounds arg2 acts as CUDA-style
// min-BLOCKS-per-CU on this toolchain: (512,4)->VGPR cap 64, (512,2)->128.
// R5's pipeline needs ~165 VGPRs -> spilled at cap 128 (557MB scratch
// writes). (512,1) -> cap 256; LDS (88KB) limits us to 1 block/CU anyway.

constexpr int DMODEL = 1024;
constexpr int NEXP   = 64;
constexpr int BM     = 128;   // tokens per block
constexpr int BK     = 64;    // K per tile
constexpr int NWAVE  = 8;
constexpr int NTOK   = 32768;
constexpr int NTILE  = DMODEL / BK;  // 16

__device__ __forceinline__ void gload16(const float* g, float* l) {
    __builtin_amdgcn_global_load_lds(
        (const __attribute__((address_space(1))) unsigned int*)g,
        (__attribute__((address_space(3))) unsigned int*)l,
        16, 0, 0);
}

__global__ __launch_bounds__(512, 1) void router_kernel(
    const float* __restrict__ x, const float* __restrict__ W,
    float* __restrict__ out, float* __restrict__ expert_sums)
{
    // xs[buf][row][64 floats]; row r stores logical 16B-chunk c at phys chunk c ^ (r&15)
    __shared__ __align__(16) float xs[2][BM][BK];
    __shared__ float lmax[NWAVE][BM];
    __shared__ float lsum[NWAVE][BM];
    __shared__ float ltv[NWAVE][BM][2];
    __shared__ int   lti[NWAVE][BM][2];

    const int tid  = threadIdx.x;
    const int lane = tid & 63;
    const int w    = tid >> 6;           // wave id 0..7
    const int tok0 = blockIdx.x * BM;

    // divergent-typed W base (vector loads, vmcnt pipe); wave-uniform value
    const float* Wb = W + (size_t)(tid >> 6) * (8 * DMODEL);

    float4 acc0[8], acc1[8];
#pragma unroll
    for (int e = 0; e < 8; ++e) {
        acc0[e] = make_float4(0.f, 0.f, 0.f, 0.f);
        acc1[e] = make_float4(0.f, 0.f, 0.f, 0.f);
    }

    // ---- staging: wave w stages rows [w*16, w*16+16) via 4 instrs x 4 rows ----
    auto stage = [&](int buf, int tile) {
#pragma unroll
        for (int i = 0; i < 4; ++i) {
            const int r0 = w * 16 + i * 4;
            const int r  = r0 + (lane >> 4);
            const int c  = lane & 15;
            const float* src = x + (size_t)(tok0 + r) * DMODEL + tile * BK
                                 + ((c ^ (r & 15)) << 2);
            float* dst = &xs[buf][r0][0] + (lane << 2);
            gload16(src, dst);
        }
    };

    stage(0, 0);
    __syncthreads();

    const int swb = lane & 15;
    int cur = 0;
    for (int tile = 0; tile < NTILE; ++tile) {
        if (tile + 1 < NTILE) stage(cur ^ 1, tile + 1);
        const float* WbT = Wb + tile * BK;

        float4 wv0[8], wv1[8];
        float4 xa0, xa1, xb0, xb1;

        // prologue: kg=0 into bank0
#pragma unroll
        for (int e = 0; e < 8; ++e)
            wv0[e] = *reinterpret_cast<const float4*>(WbT + e * DMODEL);
        {
            const int sw = (0 ^ swb) << 2;
            xa0 = *reinterpret_cast<const float4*>(&xs[cur][lane][sw]);
            xa1 = *reinterpret_cast<const float4*>(&xs[cur][lane + 64][sw]);
        }

#pragma unroll
        for (int kg2 = 0; kg2 < 8; ++kg2) {
            const int kgB = 2 * kg2 + 1;
            // prefetch kgB into bank1 (issued before FMA on bank0)
#pragma unroll
            for (int e = 0; e < 8; ++e)
                wv1[e] = *reinterpret_cast<const float4*>(
                    WbT + e * DMODEL + (kgB << 2));
            {
                const int sw = (kgB ^ swb) << 2;
                xb0 = *reinterpret_cast<const float4*>(&xs[cur][lane][sw]);
                xb1 = *reinterpret_cast<const float4*>(&xs[cur][lane + 64][sw]);
            }
            // FMA on bank0 (kg = 2*kg2)
#pragma unroll
            for (int e = 0; e < 8; ++e) {
                acc0[e].x = fmaf(xa0.x, wv0[e].x, acc0[e].x);
                acc0[e].y = fmaf(xa0.y, wv0[e].y, acc0[e].y);
                acc0[e].z = fmaf(xa0.z, wv0[e].z, acc0[e].z);
                acc0[e].w = fmaf(xa0.w, wv0[e].w, acc0[e].w);
                acc1[e].x = fmaf(xa1.x, wv0[e].x, acc1[e].x);
                acc1[e].y = fmaf(xa1.y, wv0[e].y, acc1[e].y);
                acc1[e].z = fmaf(xa1.z, wv0[e].z, acc1[e].z);
                acc1[e].w = fmaf(xa1.w, wv0[e].w, acc1[e].w);
            }
            // prefetch kg=2*kg2+2 into bank0
            if (kg2 < 7) {
                const int kgN = 2 * kg2 + 2;
#pragma unroll
                for (int e = 0; e < 8; ++e)
                    wv0[e] = *reinterpret_cast<const float4*>(
                        WbT + e * DMODEL + (kgN << 2));
                const int sw = (kgN ^ swb) << 2;
                xa0 = *reinterpret_cast<const float4*>(&xs[cur][lane][sw]);
                xa1 = *reinterpret_cast<const float4*>(&xs[cur][lane + 64][sw]);
            }
            // FMA on bank1 (kg = 2*kg2+1)
#pragma unroll
            for (int e = 0; e < 8; ++e) {
                acc0[e].x = fmaf(xb0.x, wv1[e].x, acc0[e].x);
                acc0[e].y = fmaf(xb0.y, wv1[e].y, acc0[e].y);
                acc0[e].z = fmaf(xb0.z, wv1[e].z, acc0[e].z);
                acc0[e].w = fmaf(xb0.w, wv1[e].w, acc0[e].w);
                acc1[e].x = fmaf(xb1.x, wv1[e].x, acc1[e].x);
                acc1[e].y = fmaf(xb1.y, wv1[e].y, acc1[e].y);
                acc1[e].z = fmaf(xb1.z, wv1[e].z, acc1[e].z);
                acc1[e].w = fmaf(xb1.w, wv1[e].w, acc1[e].w);
            }
        }
        __syncthreads();   // stage(t+1) drained + buf reuse guard
        cur ^= 1;
    }

    // ---- epilogue: tokens t0 = tok0+lane, t1 = tok0+lane+64 ----
    float l0[8], l1[8];
    float m0 = -INFINITY, m1 = -INFINITY;
#pragma unroll
    for (int e = 0; e < 8; ++e) {
        l0[e] = (acc0[e].x + acc0[e].y) + (acc0[e].z + acc0[e].w);
        l1[e] = (acc1[e].x + acc1[e].y) + (acc1[e].z + acc1[e].w);
        m0 = fmaxf(m0, l0[e]);
        m1 = fmaxf(m1, l1[e]);
    }
    lmax[w][lane] = m0;
    lmax[w][lane + 64] = m1;
    __syncthreads();

    float g0 = -INFINITY, g1 = -INFINITY;
#pragma unroll
    for (int ww = 0; ww < NWAVE; ++ww) {
        g0 = fmaxf(g0, lmax[ww][lane]);
        g1 = fmaxf(g1, lmax[ww][lane + 64]);
    }

    float p0[8], p1[8];
    float s0 = 0.f, s1 = 0.f;
#pragma unroll
    for (int e = 0; e < 8; ++e) {
        p0[e] = __expf(l0[e] - g0); s0 += p0[e];
        p1[e] = __expf(l1[e] - g1); s1 += p1[e];
    }
    lsum[w][lane] = s0;
    lsum[w][lane + 64] = s1;

    // local top-2 per token over this wave's 8 experts (value desc, index asc)
    {
        float v0 = -INFINITY, v1 = -INFINITY; int i0 = NEXP, i1 = NEXP;
        float u0 = -INFINITY, u1 = -INFINITY; int j0 = NEXP, j1 = NEXP;
#pragma unroll
        for (int e = 0; e < 8; ++e) {
            const int gi = w * 8 + e;
            float v = l0[e];
            if (v > v0) { v1 = v0; i1 = i0; v0 = v; i0 = gi; }
            else if (v > v1) { v1 = v; i1 = gi; }
            float u = l1[e];
            if (u > u0) { u1 = u0; j1 = j0; u0 = u; j0 = gi; }
            else if (u > u1) { u1 = u; j1 = gi; }
        }
        ltv[w][lane][0] = v0; ltv[w][lane][1] = v1;
        lti[w][lane][0] = i0; lti[w][lane][1] = i1;
        ltv[w][lane + 64][0] = u0; ltv[w][lane + 64][1] = u1;
        lti[w][lane + 64][0] = j0; lti[w][lane + 64][1] = j1;
    }
    __syncthreads();

    float gs0 = 0.f, gs1 = 0.f;
#pragma unroll
    for (int ww = 0; ww < NWAVE; ++ww) {
        gs0 += lsum[ww][lane];
        gs1 += lsum[ww][lane + 64];
    }
    const float inv0 = 1.0f / gs0;
    const float inv1 = 1.0f / gs1;

    // per-expert prob sums over this block's 128 tokens -> 1 atomic per (wave, e)
#pragma unroll
    for (int e = 0; e < 8; ++e) {
        float v = p0[e] * inv0 + p1[e] * inv1;
#pragma unroll
        for (int off = 32; off; off >>= 1) v += __shfl_xor(v, off, 64);
        if (lane == 0) atomicAdd(&expert_sums[w * 8 + e], v);
    }

    // waves 0-1 merge the 8 waves' candidates and write idx + gates
    if (tid < BM) {
        const int t = tid;
        float bv0 = -INFINITY, bv1 = -INFINITY;
        int   bi0 = NEXP, bi1 = NEXP;
#pragma unroll
        for (int ww = 0; ww < NWAVE; ++ww) {
#pragma unroll
            for (int j = 0; j < 2; ++j) {
                float v  = ltv[ww][t][j];
                int   gi = lti[ww][t][j];
                bool b0 = (v > bv0) || (v == bv0 && gi < bi0);
                if (b0) { bv1 = bv0; bi1 = bi0; bv0 = v; bi0 = gi; }
                else {
                    bool b1 = (v > bv1) || (v == bv1 && gi < bi1);
                    if (b1) { bv1 = v; bi1 = gi; }
                }
            }
        }
        float g     = __expf(bv1 - bv0);
        float denom = 1.0f + g;
        float ga = 1.0f / denom;
        float gb = g / denom;

        size_t tok = (size_t)tok0 + t;
        reinterpret_cast<float2*>(out)[tok]            = make_float2((float)bi0, (float)bi1);
        reinterpret_cast<float2*>(out + 2 * NTOK)[tok] = make_float2(ga, gb);
    }
}

__global__ void loss_kernel(const float* __restrict__ sums, float* __restrict__ out)
{
    const int lane = threadIdx.x;  // 64 threads
    float pv = sums[lane] * (1.0f / (float)NTOK);  // avg_probs[lane]
    float m = pv;
#pragma unroll
    for (int off = 32; off; off >>= 1) m += __shfl_xor(m, off, 64);
    m *= (1.0f / (float)NEXP);
    float d = pv - m;
    float v = d * d;
#pragma unroll
    for (int off = 32; off; off >>= 1) v += __shfl_xor(v, off, 64);
    v *= (1.0f / (float)(NEXP - 1));  // ddof=1
    if (lane == 0) {
        float stdv = sqrtf(v);
        float r = stdv / (m + 1e-6f);
        out[4 * NTOK] = r * r;
    }
}

extern "C" void kernel_launch(void* const* d_in, const int* in_sizes, int n_in,
                              void* d_out, int out_size, void* d_ws, size_t ws_size,
                              hipStream_t stream)
{
    const float* x = (const float*)d_in[0];
    const float* W = (const float*)d_in[1];
    float* out  = (float*)d_out;
    float* sums = (float*)d_ws;

    hipMemsetAsync(d_ws, 0, NEXP * sizeof(float), stream);

    hipLaunchKernelGGL(router_kernel, dim3(NTOK / BM), dim3(512), 0, stream,
                       x, W, out, sums);
    hipLaunchKernelGGL(loss_kernel, dim3(1), dim3(64), 0, stream, sums, out);
}

// Round 7
// 404.122 us; speedup vs baseline: 1.1061x; 1.1055x over previous
//
#include <hip/hip_runtime.h>
#include <math.h>

// Router: x (4,8192,1024) f32, W (64,1024) f32
// out = [ top_idx (32768,2) as float | top_gates (32768,2) | loss (1) ]
// ws  = 64 floats of per-expert prob sums (atomic accumulated)
//
// R7: fit the ping-pong pipeline under the MEASURED 128-VGPR clamp.
// Measured ladder: (512,4)->64 VGPR, (512,2)->128, (512,1)->128 (clamped!)
// -> allocator will not exceed 128 for 512-thread blocks. So shrink the
// wave tile: BM=64 tokens/block, each wave = 64 tokens x 8 experts.
// Budget: acc 32 + W banks 64 + x 8 + addr ~15 = ~119 < 128. Also gives
// 2 blocks/CU (4 waves/SIMD, ~50% occupancy) for TLP + barrier overlap.

constexpr int DMODEL = 1024;
constexpr int NEXP   = 64;
constexpr int BM     = 64;    // tokens per block
constexpr int BK     = 64;    // K per tile
constexpr int NWAVE  = 8;
constexpr int NTOK   = 32768;
constexpr int NTILE  = DMODEL / BK;  // 16

__device__ __forceinline__ void gload16(const float* g, float* l) {
    __builtin_amdgcn_global_load_lds(
        (const __attribute__((address_space(1))) unsigned int*)g,
        (__attribute__((address_space(3))) unsigned int*)l,
        16, 0, 0);
}

__global__ __launch_bounds__(512, 2) void router_kernel(
    const float* __restrict__ x, const float* __restrict__ W,
    float* __restrict__ out, float* __restrict__ expert_sums)
{
    // xs[buf][row][64 floats]; row r stores logical 16B-chunk c at phys c ^ (r&15)
    __shared__ __align__(16) float xs[2][BM][BK];   // 32 KB
    __shared__ float lmax[NWAVE][BM];
    __shared__ float lsum[NWAVE][BM];
    __shared__ float ltv[NWAVE][BM][2];
    __shared__ int   lti[NWAVE][BM][2];

    const int tid  = threadIdx.x;
    const int lane = tid & 63;
    const int w    = tid >> 6;           // wave id 0..7
    const int tok0 = blockIdx.x * BM;

    // divergent-typed W base (vector loads, vmcnt pipe); wave-uniform value
    const float* Wb = W + (size_t)(tid >> 6) * (8 * DMODEL);

    float4 acc[8];
#pragma unroll
    for (int e = 0; e < 8; ++e) acc[e] = make_float4(0.f, 0.f, 0.f, 0.f);

    // ---- staging: wave w stages rows [w*8, w*8+8); 2 instrs x 4 rows each ----
    auto stage = [&](int buf, int tile) {
#pragma unroll
        for (int i = 0; i < 2; ++i) {
            const int r0 = w * 8 + i * 4;
            const int r  = r0 + (lane >> 4);
            const int c  = lane & 15;
            const float* src = x + (size_t)(tok0 + r) * DMODEL + tile * BK
                                 + ((c ^ (r & 15)) << 2);
            float* dst = &xs[buf][r0][0] + (lane << 2);
            gload16(src, dst);
        }
    };

    stage(0, 0);
    __syncthreads();

    const int swb = lane & 15;
    int cur = 0;
    for (int tile = 0; tile < NTILE; ++tile) {
        if (tile + 1 < NTILE) stage(cur ^ 1, tile + 1);
        const float* WbT = Wb + tile * BK;

        float4 wv0[8], wv1[8];
        float4 xa, xb;

        // prologue: kg=0 into bank0
#pragma unroll
        for (int e = 0; e < 8; ++e)
            wv0[e] = *reinterpret_cast<const float4*>(WbT + e * DMODEL);
        xa = *reinterpret_cast<const float4*>(&xs[cur][lane][(0 ^ swb) << 2]);

#pragma unroll
        for (int kg2 = 0; kg2 < 8; ++kg2) {
            const int kgB = 2 * kg2 + 1;
            // prefetch kgB into bank1 (issued before FMA on bank0)
#pragma unroll
            for (int e = 0; e < 8; ++e)
                wv1[e] = *reinterpret_cast<const float4*>(
                    WbT + e * DMODEL + (kgB << 2));
            xb = *reinterpret_cast<const float4*>(
                &xs[cur][lane][(kgB ^ swb) << 2]);
            // FMA on bank0 (kg = 2*kg2)
#pragma unroll
            for (int e = 0; e < 8; ++e) {
                acc[e].x = fmaf(xa.x, wv0[e].x, acc[e].x);
                acc[e].y = fmaf(xa.y, wv0[e].y, acc[e].y);
                acc[e].z = fmaf(xa.z, wv0[e].z, acc[e].z);
                acc[e].w = fmaf(xa.w, wv0[e].w, acc[e].w);
            }
            // prefetch kg = 2*kg2+2 into bank0
            if (kg2 < 7) {
                const int kgN = 2 * kg2 + 2;
#pragma unroll
                for (int e = 0; e < 8; ++e)
                    wv0[e] = *reinterpret_cast<const float4*>(
                        WbT + e * DMODEL + (kgN << 2));
                xa = *reinterpret_cast<const float4*>(
                    &xs[cur][lane][(kgN ^ swb) << 2]);
            }
            // FMA on bank1 (kg = 2*kg2+1)
#pragma unroll
            for (int e = 0; e < 8; ++e) {
                acc[e].x = fmaf(xb.x, wv1[e].x, acc[e].x);
                acc[e].y = fmaf(xb.y, wv1[e].y, acc[e].y);
                acc[e].z = fmaf(xb.z, wv1[e].z, acc[e].z);
                acc[e].w = fmaf(xb.w, wv1[e].w, acc[e].w);
            }
        }
        __syncthreads();   // stage(t+1) drained + buf reuse guard
        cur ^= 1;
    }

    // ---- epilogue: token t = tok0 + lane ----
    float logit[8];
    float lm = -INFINITY;
#pragma unroll
    for (int e = 0; e < 8; ++e) {
        logit[e] = (acc[e].x + acc[e].y) + (acc[e].z + acc[e].w);
        lm = fmaxf(lm, logit[e]);
    }
    lmax[w][lane] = lm;
    __syncthreads();

    float gmax = -INFINITY;
#pragma unroll
    for (int ww = 0; ww < NWAVE; ++ww) gmax = fmaxf(gmax, lmax[ww][lane]);

    float p[8];
    float s = 0.f;
#pragma unroll
    for (int e = 0; e < 8; ++e) { p[e] = __expf(logit[e] - gmax); s += p[e]; }
    lsum[w][lane] = s;

    // local top-2 over this wave's 8 experts (value desc, index asc)
    {
        float v0 = -INFINITY, v1 = -INFINITY; int i0 = NEXP, i1 = NEXP;
#pragma unroll
        for (int e = 0; e < 8; ++e) {
            const int gi = w * 8 + e;
            float v = logit[e];
            if (v > v0) { v1 = v0; i1 = i0; v0 = v; i0 = gi; }
            else if (v > v1) { v1 = v; i1 = gi; }
        }
        ltv[w][lane][0] = v0; ltv[w][lane][1] = v1;
        lti[w][lane][0] = i0; lti[w][lane][1] = i1;
    }
    __syncthreads();

    float gsum = 0.f;
#pragma unroll
    for (int ww = 0; ww < NWAVE; ++ww) gsum += lsum[ww][lane];
    const float inv = 1.0f / gsum;

    // per-expert prob sums over this block's 64 tokens -> 1 atomic per (wave, e)
#pragma unroll
    for (int e = 0; e < 8; ++e) {
        float v = p[e] * inv;
#pragma unroll
        for (int off = 32; off; off >>= 1) v += __shfl_xor(v, off, 64);
        if (lane == 0) atomicAdd(&expert_sums[w * 8 + e], v);
    }

    // wave 0 merges the 8 waves' candidates and writes idx + gates
    if (tid < BM) {
        const int t = tid;
        float bv0 = -INFINITY, bv1 = -INFINITY;
        int   bi0 = NEXP, bi1 = NEXP;
#pragma unroll
        for (int ww = 0; ww < NWAVE; ++ww) {
#pragma unroll
            for (int j = 0; j < 2; ++j) {
                float v  = ltv[ww][t][j];
                int   gi = lti[ww][t][j];
                bool b0 = (v > bv0) || (v == bv0 && gi < bi0);
                if (b0) { bv1 = bv0; bi1 = bi0; bv0 = v; bi0 = gi; }
                else {
                    bool b1 = (v > bv1) || (v == bv1 && gi < bi1);
                    if (b1) { bv1 = v; bi1 = gi; }
                }
            }
        }
        float g     = __expf(bv1 - bv0);
        float denom = 1.0f + g;
        float ga = 1.0f / denom;
        float gb = g / denom;

        size_t tok = (size_t)tok0 + t;
        reinterpret_cast<float2*>(out)[tok]            = make_float2((float)bi0, (float)bi1);
        reinterpret_cast<float2*>(out + 2 * NTOK)[tok] = make_float2(ga, gb);
    }
}

__global__ void loss_kernel(const float* __restrict__ sums, float* __restrict__ out)
{
    const int lane = threadIdx.x;  // 64 threads
    float pv = sums[lane] * (1.0f / (float)NTOK);  // avg_probs[lane]
    float m = pv;
#pragma unroll
    for (int off = 32; off; off >>= 1) m += __shfl_xor(m, off, 64);
    m *= (1.0f / (float)NEXP);
    float d = pv - m;
    float v = d * d;
#pragma unroll
    for (int off = 32; off; off >>= 1) v += __shfl_xor(v, off, 64);
    v *= (1.0f / (float)(NEXP - 1));  // ddof=1
    if (lane == 0) {
        float stdv = sqrtf(v);
        float r = stdv / (m + 1e-6f);
        out[4 * NTOK] = r * r;
    }
}

extern "C" void kernel_launch(void* const* d_in, const int* in_sizes, int n_in,
                              void* d_out, int out_size, void* d_ws, size_t ws_size,
                              hipStream_t stream)
{
    const float* x = (const float*)d_in[0];
    const float* W = (const float*)d_in[1];
    float* out  = (float*)d_out;
    float* sums = (float*)d_ws;

    hipMemsetAsync(d_ws, 0, NEXP * sizeof(float), stream);

    hipLaunchKernelGGL(router_kernel, dim3(NTOK / BM), dim3(512), 0, stream,
                       x, W, out, sums);
    hipLaunchKernelGGL(loss_kernel, dim3(1), dim3(64), 0, stream, sums, out);
}

// Round 8
// 184.997 us; speedup vs baseline: 2.4163x; 2.1845x over previous
//
#include <hip/hip_runtime.h>
#include <math.h>

// Router: x (4,8192,1024) f32, W (64,1024) f32
// out = [ top_idx (32768,2) as float | top_gates (32768,2) | loss (1) ]
// ws  = 64 floats of per-expert prob sums (atomic accumulated)
//
// R8: W through LDS broadcast. Measured R3-R7: wave-uniform VMEM loads pay
// full TA cost (~48cy each; 64/kg/CU = 3100cy/kg = the whole R4 runtime);
// scalar path serializes on lgkmcnt drains (R1/R2, 16% VALU). LDS uniform-
// address ds_read is a true broadcast (4 banks, no TA). Stage the 16KB W
// k-tile into LDS per tile; inner loop = pure DS + FMA.

constexpr int DMODEL = 1024;
constexpr int NEXP   = 64;
constexpr int BM     = 128;   // tokens per block
constexpr int BK     = 64;    // K per tile
constexpr int NWAVE  = 8;
constexpr int NTOK   = 32768;
constexpr int NTILE  = DMODEL / BK;  // 16

__device__ __forceinline__ void gload16(const float* g, float* l) {
    __builtin_amdgcn_global_load_lds(
        (const __attribute__((address_space(1))) unsigned int*)g,
        (__attribute__((address_space(3))) unsigned int*)l,
        16, 0, 0);
}

__global__ __launch_bounds__(512, 1) void router_kernel(
    const float* __restrict__ x, const float* __restrict__ W,
    float* __restrict__ out, float* __restrict__ expert_sums)
{
    // xs: row r stores logical 16B-chunk c at phys chunk c ^ (r&15)  (64 KB)
    __shared__ __align__(16) float xs[2][BM][BK];
    // Wt: [kg][e] -> W[e][k0+4kg .. k0+4kg+3]  (32 KB, linear)
    __shared__ __align__(16) float Wt[2][BK / 4][NEXP][4];
    __shared__ float lmax[NWAVE][BM];
    __shared__ float lsum[NWAVE][BM];
    __shared__ float ltv[NWAVE][BM][2];
    __shared__ int   lti[NWAVE][BM][2];

    const int tid  = threadIdx.x;
    const int lane = tid & 63;
    const int w    = tid >> 6;           // wave id 0..7
    const int tok0 = blockIdx.x * BM;

    float4 acc0[8], acc1[8];
#pragma unroll
    for (int e = 0; e < 8; ++e) {
        acc0[e] = make_float4(0.f, 0.f, 0.f, 0.f);
        acc1[e] = make_float4(0.f, 0.f, 0.f, 0.f);
    }

    // ---- x staging: wave w stages rows [w*16, w*16+16); 4 instrs ----
    auto stageX = [&](int buf, int tile) {
#pragma unroll
        for (int i = 0; i < 4; ++i) {
            const int r0 = w * 16 + i * 4;
            const int r  = r0 + (lane >> 4);
            const int c  = lane & 15;
            const float* src = x + (size_t)(tok0 + r) * DMODEL + tile * BK
                                 + ((c ^ (r & 15)) << 2);
            float* dst = &xs[buf][r0][0] + (lane << 2);
            gload16(src, dst);
        }
    };
    // ---- W staging: wave w stages kg = {w, 8+w}; lane = expert ----
    auto stageW = [&](int buf, int tile) {
#pragma unroll
        for (int i = 0; i < 2; ++i) {
            const int kg = i * 8 + w;    // wave-uniform
            const float* src = W + (size_t)lane * DMODEL + tile * BK + kg * 4;
            float* dst = &Wt[buf][kg][0][0] + (lane << 2);
            gload16(src, dst);
        }
    };

    stageX(0, 0);
    stageW(0, 0);
    __syncthreads();

    const int swb = lane & 15;
    const int e0  = w * 8;               // this wave's first expert
    int cur = 0;
    for (int tile = 0; tile < NTILE; ++tile) {
        if (tile + 1 < NTILE) {
            stageX(cur ^ 1, tile + 1);
            stageW(cur ^ 1, tile + 1);
        }
#pragma unroll 4
        for (int kg = 0; kg < BK / 4; ++kg) {
            const int sw = (kg ^ swb) << 2;
            const float4 xv0 = *reinterpret_cast<const float4*>(&xs[cur][lane][sw]);
            const float4 xv1 = *reinterpret_cast<const float4*>(&xs[cur][lane + 64][sw]);
            float4 wv[8];
#pragma unroll
            for (int e = 0; e < 8; ++e)
                wv[e] = *reinterpret_cast<const float4*>(&Wt[cur][kg][e0 + e][0]);
#pragma unroll
            for (int e = 0; e < 8; ++e) {
                acc0[e].x = fmaf(xv0.x, wv[e].x, acc0[e].x);
                acc0[e].y = fmaf(xv0.y, wv[e].y, acc0[e].y);
                acc0[e].z = fmaf(xv0.z, wv[e].z, acc0[e].z);
                acc0[e].w = fmaf(xv0.w, wv[e].w, acc0[e].w);
                acc1[e].x = fmaf(xv1.x, wv[e].x, acc1[e].x);
                acc1[e].y = fmaf(xv1.y, wv[e].y, acc1[e].y);
                acc1[e].z = fmaf(xv1.z, wv[e].z, acc1[e].z);
                acc1[e].w = fmaf(xv1.w, wv[e].w, acc1[e].w);
            }
        }
        __syncthreads();   // next tile staged (vmcnt drain) + LDS reuse guard
        cur ^= 1;
    }

    // ---- epilogue: tokens t0 = tok0+lane, t1 = tok0+lane+64 ----
    float l0[8], l1[8];
    float m0 = -INFINITY, m1 = -INFINITY;
#pragma unroll
    for (int e = 0; e < 8; ++e) {
        l0[e] = (acc0[e].x + acc0[e].y) + (acc0[e].z + acc0[e].w);
        l1[e] = (acc1[e].x + acc1[e].y) + (acc1[e].z + acc1[e].w);
        m0 = fmaxf(m0, l0[e]);
        m1 = fmaxf(m1, l1[e]);
    }
    lmax[w][lane] = m0;
    lmax[w][lane + 64] = m1;
    __syncthreads();

    float g0 = -INFINITY, g1 = -INFINITY;
#pragma unroll
    for (int ww = 0; ww < NWAVE; ++ww) {
        g0 = fmaxf(g0, lmax[ww][lane]);
        g1 = fmaxf(g1, lmax[ww][lane + 64]);
    }

    float p0[8], p1[8];
    float s0 = 0.f, s1 = 0.f;
#pragma unroll
    for (int e = 0; e < 8; ++e) {
        p0[e] = __expf(l0[e] - g0); s0 += p0[e];
        p1[e] = __expf(l1[e] - g1); s1 += p1[e];
    }
    lsum[w][lane] = s0;
    lsum[w][lane + 64] = s1;

    // local top-2 per token over this wave's 8 experts (value desc, index asc)
    {
        float v0 = -INFINITY, v1 = -INFINITY; int i0 = NEXP, i1 = NEXP;
        float u0 = -INFINITY, u1 = -INFINITY; int j0 = NEXP, j1 = NEXP;
#pragma unroll
        for (int e = 0; e < 8; ++e) {
            const int gi = e0 + e;
            float v = l0[e];
            if (v > v0) { v1 = v0; i1 = i0; v0 = v; i0 = gi; }
            else if (v > v1) { v1 = v; i1 = gi; }
            float u = l1[e];
            if (u > u0) { u1 = u0; j1 = j0; u0 = u; j0 = gi; }
            else if (u > u1) { u1 = u; j1 = gi; }
        }
        ltv[w][lane][0] = v0; ltv[w][lane][1] = v1;
        lti[w][lane][0] = i0; lti[w][lane][1] = i1;
        ltv[w][lane + 64][0] = u0; ltv[w][lane + 64][1] = u1;
        lti[w][lane + 64][0] = j0; lti[w][lane + 64][1] = j1;
    }
    __syncthreads();

    float gs0 = 0.f, gs1 = 0.f;
#pragma unroll
    for (int ww = 0; ww < NWAVE; ++ww) {
        gs0 += lsum[ww][lane];
        gs1 += lsum[ww][lane + 64];
    }
    const float inv0 = 1.0f / gs0;
    const float inv1 = 1.0f / gs1;

    // per-expert prob sums over this block's 128 tokens -> 1 atomic per (wave, e)
#pragma unroll
    for (int e = 0; e < 8; ++e) {
        float v = p0[e] * inv0 + p1[e] * inv1;
#pragma unroll
        for (int off = 32; off; off >>= 1) v += __shfl_xor(v, off, 64);
        if (lane == 0) atomicAdd(&expert_sums[e0 + e], v);
    }

    // waves 0-1 merge the 8 waves' candidates and write idx + gates
    if (tid < BM) {
        const int t = tid;
        float bv0 = -INFINITY, bv1 = -INFINITY;
        int   bi0 = NEXP, bi1 = NEXP;
#pragma unroll
        for (int ww = 0; ww < NWAVE; ++ww) {
#pragma unroll
            for (int j = 0; j < 2; ++j) {
                float v  = ltv[ww][t][j];
                int   gi = lti[ww][t][j];
                bool b0 = (v > bv0) || (v == bv0 && gi < bi0);
                if (b0) { bv1 = bv0; bi1 = bi0; bv0 = v; bi0 = gi; }
                else {
                    bool b1 = (v > bv1) || (v == bv1 && gi < bi1);
                    if (b1) { bv1 = v; bi1 = gi; }
                }
            }
        }
        float g     = __expf(bv1 - bv0);
        float denom = 1.0f + g;
        float ga = 1.0f / denom;
        float gb = g / denom;

        size_t tok = (size_t)tok0 + t;
        reinterpret_cast<float2*>(out)[tok]            = make_float2((float)bi0, (float)bi1);
        reinterpret_cast<float2*>(out + 2 * NTOK)[tok] = make_float2(ga, gb);
    }
}

__global__ void loss_kernel(const float* __restrict__ sums, float* __restrict__ out)
{
    const int lane = threadIdx.x;  // 64 threads
    float pv = sums[lane] * (1.0f / (float)NTOK);  // avg_probs[lane]
    float m = pv;
#pragma unroll
    for (int off = 32; off; off >>= 1) m += __shfl_xor(m, off, 64);
    m *= (1.0f / (float)NEXP);
    float d = pv - m;
    float v = d * d;
#pragma unroll
    for (int off = 32; off; off >>= 1) v += __shfl_xor(v, off, 64);
    v *= (1.0f / (float)(NEXP - 1));  // ddof=1
    if (lane == 0) {
        float stdv = sqrtf(v);
        float r = stdv / (m + 1e-6f);
        out[4 * NTOK] = r * r;
    }
}

extern "C" void kernel_launch(void* const* d_in, const int* in_sizes, int n_in,
                              void* d_out, int out_size, void* d_ws, size_t ws_size,
                              hipStream_t stream)
{
    const float* x = (const float*)d_in[0];
    const float* W = (const float*)d_in[1];
    float* out  = (float*)d_out;
    float* sums = (float*)d_ws;

    hipMemsetAsync(d_ws, 0, NEXP * sizeof(float), stream);

    hipLaunchKernelGGL(router_kernel, dim3(NTOK / BM), dim3(512), 0, stream,
                       x, W, out, sums);
    hipLaunchKernelGGL(loss_kernel, dim3(1), dim3(64), 0, stream, sums, out);
}